// Round 2
// baseline (378.525 us; speedup 1.0000x reference)
//
#include <hip/hip_runtime.h>
#include <math.h>

// Problem constants
#define NPIX   131072      // 32 * 64 * 64 pixels
#define KCODES 512
#define DDIM   64
#define HWSZ   4096        // 64*64
#define NELEM  8388608     // NPIX * DDIM

// d_out layout (fp32): [0]=loss, [1..1+NELEM)=q_nchw, [1+NELEM]=perplexity,
// [2+NELEM .. 2+2*NELEM)=q_nhwc flat
#define OUT_NCHW_OFF 1
#define OUT_PERP_IDX (1 + NELEM)
#define OUT_NHWC_OFF (2 + NELEM)

// ws layout (fp32 words): [0]=loss accum, [16..16+512)=norms, [544..1056)=counts(uint)
#define WS_NORM_OFF 16
#define WS_CNT_OFF  544

__global__ __launch_bounds__(512) void vq_norms(const float* __restrict__ emb,
                                                float* __restrict__ ws) {
    int k = threadIdx.x;  // 512 threads
    const float4* e4 = reinterpret_cast<const float4*>(emb + k * DDIM);
    float s = 0.f;
#pragma unroll
    for (int i = 0; i < 16; ++i) {
        float4 v = e4[i];
        s = fmaf(v.x, v.x, s);
        s = fmaf(v.y, v.y, s);
        s = fmaf(v.z, v.z, s);
        s = fmaf(v.w, v.w, s);
    }
    ws[WS_NORM_OFF + k] = s;
}

// min 2 waves/EU -> VGPR cap 256: keeps x[64] in registers (VGPR=44 + scratch
// spill at default heuristic was the R1 bottleneck). Grid caps occupancy at
// 2 blocks/CU anyway, so the relaxed register budget costs nothing.
__global__ __launch_bounds__(256, 2) void vq_main(const float* __restrict__ in,
                                                  const float* __restrict__ emb,
                                                  float* __restrict__ out,
                                                  float* __restrict__ ws) {
    __shared__ float    q_lds[64 * 65];   // padded tile: 64 pixels x 64 ch
    __shared__ int      idx_lds[256];
    __shared__ unsigned cnt_lds[KCODES];
    __shared__ float    red[4];

    const int t = threadIdx.x;
    cnt_lds[t] = 0u;
    cnt_lds[t + 256] = 0u;
    __syncthreads();

    const int pix0 = blockIdx.x << 8;   // 256 pixels per block, never straddles images
    const int b    = pix0 >> 12;        // image index
    const int hwb  = pix0 & (HWSZ - 1); // hw base within image

    // Load this thread's pixel vector (coalesced across lanes; stride HWSZ per channel)
    const float* inb = in + b * (DDIM * HWSZ) + hwb + t;
    float x[DDIM];
#pragma unroll
    for (int c = 0; c < DDIM; ++c) x[c] = inb[c * HWSZ];
    float x2 = 0.f;
#pragma unroll
    for (int c = 0; c < DDIM; ++c) x2 = fmaf(x[c], x[c], x2);

    // Distance argmin: dist_k = |e_k|^2 - 2 x.e_k  (|x|^2 added only for loss)
    const float* __restrict__ nrm = ws + WS_NORM_OFF;
    float best = 3.4e38f;
    int   bidx = 0;
    for (int k = 0; k < KCODES; k += 8) {
        float acc[8];
#pragma unroll
        for (int j = 0; j < 8; ++j) acc[j] = 0.f;
#pragma unroll
        for (int c = 0; c < DDIM; c += 4) {
#pragma unroll
            for (int j = 0; j < 8; ++j) {
                // wave-uniform address -> scalar-load promotable
                const float4 e = *reinterpret_cast<const float4*>(emb + (k + j) * DDIM + c);
                acc[j] = fmaf(x[c + 0], e.x, acc[j]);
                acc[j] = fmaf(x[c + 1], e.y, acc[j]);
                acc[j] = fmaf(x[c + 2], e.z, acc[j]);
                acc[j] = fmaf(x[c + 3], e.w, acc[j]);
            }
        }
#pragma unroll
        for (int j = 0; j < 8; ++j) {
            float dj = fmaf(-2.f, acc[j], nrm[k + j]);
            if (dj < best) { best = dj; bidx = k + j; }  // strict < => first min (ref argmin)
        }
    }

    // loss contribution: |x - e_best|^2 = x2 + best
    float lp = x2 + best;
#pragma unroll
    for (int o = 32; o > 0; o >>= 1) lp += __shfl_xor(lp, o, 64);
    if ((t & 63) == 0) red[t >> 6] = lp;

    idx_lds[t] = bidx;
    atomicAdd(&cnt_lds[bidx], 1u);
    __syncthreads();

    if (t == 0) atomicAdd(ws, red[0] + red[1] + red[2] + red[3]);
    unsigned* gcnt = reinterpret_cast<unsigned*>(ws) + WS_CNT_OFF;
    atomicAdd(gcnt + t, cnt_lds[t]);
    atomicAdd(gcnt + t + 256, cnt_lds[t + 256]);

    // Epilogue: 4 subtiles of 64 pixels; stage gathered rows in padded LDS so both
    // NHWC and NCHW writes are fully coalesced and LDS reads conflict-free.
    float* out2 = out + OUT_NCHW_OFF;   // NCHW
    float* out3 = out + OUT_NHWC_OFF;   // NHWC flat (float2-aligned, NOT float4-aligned)
    const float2* emb2 = reinterpret_cast<const float2*>(emb);
    float2* out3_2 = reinterpret_cast<float2*>(out3);

    for (int s = 0; s < 4; ++s) {
        // fill: 64 pixels x 32 float2 = 2048 float2, 256 threads -> 8 iters
#pragma unroll
        for (int it = 0; it < 8; ++it) {
            int fid = it * 256 + t;
            int pp  = fid >> 5;        // 0..63 local pixel
            int c2  = fid & 31;        // float2 column
            int row = idx_lds[s * 64 + pp];
            float2 v = emb2[row * 32 + c2];
            out3_2[(size_t)(pix0 + s * 64 + pp) * 32 + c2] = v;  // coalesced NHWC
            q_lds[pp * 65 + c2 * 2 + 0] = v.x;
            q_lds[pp * 65 + c2 * 2 + 1] = v.y;
        }
        __syncthreads();
        // drain NCHW: 64 ch x 64 hw, lanes sweep hw -> coalesced; (hwl+c)%32 -> no conflicts
#pragma unroll
        for (int it = 0; it < 16; ++it) {
            int did = it * 256 + t;
            int c   = did >> 6;
            int hwl = did & 63;
            out2[(size_t)(b * DDIM + c) * HWSZ + hwb + s * 64 + hwl] = q_lds[hwl * 65 + c];
        }
        __syncthreads();
    }
}

__global__ __launch_bounds__(256) void vq_fin(float* __restrict__ out,
                                              const float* __restrict__ ws) {
    const unsigned* cnt = reinterpret_cast<const unsigned*>(ws) + WS_CNT_OFF;
    int t = threadIdx.x;  // 256
    double s = 0.0;
#pragma unroll
    for (int k = t; k < KCODES; k += 256) {
        double p = (double)cnt[k] / (double)NPIX;
        s += p * log(p + 1e-10);
    }
#pragma unroll
    for (int o = 32; o > 0; o >>= 1) s += __shfl_xor(s, o, 64);
    __shared__ double rd[4];
    if ((t & 63) == 0) rd[t >> 6] = s;
    __syncthreads();
    if (t == 0) {
        double tot = rd[0] + rd[1] + rd[2] + rd[3];
        out[OUT_PERP_IDX] = (float)exp(-tot);
        out[0] = 0.25f * ws[0] / (float)NELEM;
    }
}

extern "C" void kernel_launch(void* const* d_in, const int* in_sizes, int n_in,
                              void* d_out, int out_size, void* d_ws, size_t ws_size,
                              hipStream_t stream) {
    const float* in  = (const float*)d_in[0];
    const float* emb = (const float*)d_in[1];
    float* out = (float*)d_out;
    float* ws  = (float*)d_ws;

    // zero loss accumulator + norms + counts (ws is re-poisoned before every launch)
    hipMemsetAsync(d_ws, 0, (WS_CNT_OFF + KCODES) * sizeof(float), stream);
    vq_norms<<<1, 512, 0, stream>>>(emb, ws);
    vq_main<<<NPIX / 256, 256, 0, stream>>>(in, emb, out, ws);
    vq_fin<<<1, 256, 0, stream>>>(out, ws);
}

// Round 3
// 315.334 us; speedup vs baseline: 1.2004x; 1.2004x over previous
//
#include <hip/hip_runtime.h>
#include <math.h>

// Problem constants
#define NPIX   131072      // 32 * 64 * 64 pixels
#define KCODES 512
#define DDIM   64
#define HWSZ   4096        // 64*64
#define NELEM  8388608     // NPIX * DDIM

// d_out layout (fp32): [0]=loss, [1..1+NELEM)=q_nchw, [1+NELEM]=perplexity,
// [2+NELEM .. 2+2*NELEM)=q_nhwc flat
#define OUT_NCHW_OFF 1
#define OUT_PERP_IDX (1 + NELEM)
#define OUT_NHWC_OFF (2 + NELEM)

// ws layout (fp32 words): [0]=loss accum, [544..1056)=counts(uint)
#define WS_CNT_OFF  544

// R2 post-mortem: VGPR=44 regardless of launch_bounds => compiler keeps x[64]
// in scratch/reloads, every FMA reads memory => 300us latency-bound.
// Fix: x lives in LDS transposed [d][pixel]; thread t touches only column t
// (lanes consecutive -> 2-way bank aliasing -> free). Register state is only
// acc[16] + 4 x floats. e comes from wave-uniform s_load_dwordx4.
__global__ __launch_bounds__(256, 2) void vq_main(const float* __restrict__ in,
                                                  const float* __restrict__ emb,
                                                  float* __restrict__ out,
                                                  float* __restrict__ ws) {
    __shared__ float    smem[DDIM * 256];  // x transposed [d][256 pix]; reused as q tile
    __shared__ float    nrm_lds[KCODES];
    __shared__ int      idx_lds[256];
    __shared__ unsigned cnt_lds[KCODES];
    __shared__ float    red[4];

    const int t = threadIdx.x;
    cnt_lds[t] = 0u;
    cnt_lds[t + 256] = 0u;

    const int pix0 = blockIdx.x << 8;   // 256 pixels per block, never straddles images
    const int b    = pix0 >> 12;        // image index
    const int hwb  = pix0 & (HWSZ - 1); // hw base within image

    // Stage this thread's pixel vector into LDS column t (coalesced global reads;
    // ds_write lanes consecutive -> conflict-free). fp order identical to R1.
    const float* inb = in + b * (DDIM * HWSZ) + hwb + t;
    float x2 = 0.f;
#pragma unroll
    for (int c = 0; c < DDIM; ++c) {
        float v = inb[c * HWSZ];
        smem[c * 256 + t] = v;
        x2 = fmaf(v, v, x2);
    }

    // |e_k|^2 fused here (2 codes/thread), identical fmaf chain to old vq_norms.
    {
        const float4* e4 = reinterpret_cast<const float4*>(emb + t * DDIM);
        float s = 0.f;
#pragma unroll
        for (int i = 0; i < 16; ++i) {
            float4 v = e4[i];
            s = fmaf(v.x, v.x, s); s = fmaf(v.y, v.y, s);
            s = fmaf(v.z, v.z, s); s = fmaf(v.w, v.w, s);
        }
        nrm_lds[t] = s;
        const float4* e4b = reinterpret_cast<const float4*>(emb + (t + 256) * DDIM);
        s = 0.f;
#pragma unroll
        for (int i = 0; i < 16; ++i) {
            float4 v = e4b[i];
            s = fmaf(v.x, v.x, s); s = fmaf(v.y, v.y, s);
            s = fmaf(v.z, v.z, s); s = fmaf(v.w, v.w, s);
        }
        nrm_lds[t + 256] = s;
    }
    __syncthreads();

    // Distance argmin: dist_k = |e_k|^2 - 2 x.e_k ; per-code fp order (d ascending,
    // 4 sequential fmafs) identical to the passing R1 kernel.
    float best = 3.4e38f;
    int   bidx = 0;
    for (int k = 0; k < KCODES; k += 16) {
        float acc[16];
#pragma unroll
        for (int j = 0; j < 16; ++j) acc[j] = 0.f;
        for (int d4 = 0; d4 < 16; ++d4) {
            // x for 4 channels of my pixel: ds_read_b32, lanes consecutive -> free
            const float xa = smem[(4 * d4 + 0) * 256 + t];
            const float xb = smem[(4 * d4 + 1) * 256 + t];
            const float xc = smem[(4 * d4 + 2) * 256 + t];
            const float xd = smem[(4 * d4 + 3) * 256 + t];
#pragma unroll
            for (int j = 0; j < 16; ++j) {
                // wave-uniform address -> s_load_dwordx4; SGPR operand in v_fmac
                const float4 e = *reinterpret_cast<const float4*>(emb + (k + j) * DDIM + 4 * d4);
                acc[j] = fmaf(xa, e.x, acc[j]);
                acc[j] = fmaf(xb, e.y, acc[j]);
                acc[j] = fmaf(xc, e.z, acc[j]);
                acc[j] = fmaf(xd, e.w, acc[j]);
            }
        }
#pragma unroll
        for (int j = 0; j < 16; ++j) {
            float dj = fmaf(-2.f, acc[j], nrm_lds[k + j]);  // nrm: LDS broadcast (free)
            if (dj < best) { best = dj; bidx = k + j; }     // strict < => first-min, as ref
        }
    }

    // loss contribution: |x - e_best|^2 = x2 + best
    float lp = x2 + best;
#pragma unroll
    for (int o = 32; o > 0; o >>= 1) lp += __shfl_xor(lp, o, 64);
    if ((t & 63) == 0) red[t >> 6] = lp;

    idx_lds[t] = bidx;
    atomicAdd(&cnt_lds[bidx], 1u);
    __syncthreads();

    if (t == 0) atomicAdd(ws, red[0] + red[1] + red[2] + red[3]);
    unsigned* gcnt = reinterpret_cast<unsigned*>(ws) + WS_CNT_OFF;
    atomicAdd(gcnt + t, cnt_lds[t]);
    atomicAdd(gcnt + t + 256, cnt_lds[t + 256]);

    // Epilogue: 4 subtiles of 64 pixels; stage gathered rows in padded LDS tile
    // (aliases smem - x data dead past the barrier above) so both NHWC and NCHW
    // writes are fully coalesced and LDS reads conflict-free.
    float* q_lds = smem;                // [64][65] padded tile, 16.6KB of the 64KB region
    float* out2 = out + OUT_NCHW_OFF;   // NCHW
    float* out3 = out + OUT_NHWC_OFF;   // NHWC flat (float2-aligned, NOT float4-aligned)
    const float2* emb2 = reinterpret_cast<const float2*>(emb);
    float2* out3_2 = reinterpret_cast<float2*>(out3);

    for (int s = 0; s < 4; ++s) {
#pragma unroll
        for (int it = 0; it < 8; ++it) {
            int fid = it * 256 + t;
            int pp  = fid >> 5;        // 0..63 local pixel
            int c2  = fid & 31;        // float2 column
            int row = idx_lds[s * 64 + pp];
            float2 v = emb2[row * 32 + c2];
            out3_2[(size_t)(pix0 + s * 64 + pp) * 32 + c2] = v;  // coalesced NHWC
            q_lds[pp * 65 + c2 * 2 + 0] = v.x;
            q_lds[pp * 65 + c2 * 2 + 1] = v.y;
        }
        __syncthreads();
#pragma unroll
        for (int it = 0; it < 16; ++it) {
            int did = it * 256 + t;
            int c   = did >> 6;
            int hwl = did & 63;
            out2[(size_t)(b * DDIM + c) * HWSZ + hwb + s * 64 + hwl] = q_lds[hwl * 65 + c];
        }
        __syncthreads();
    }
}

__global__ __launch_bounds__(256) void vq_fin(float* __restrict__ out,
                                              const float* __restrict__ ws) {
    const unsigned* cnt = reinterpret_cast<const unsigned*>(ws) + WS_CNT_OFF;
    int t = threadIdx.x;  // 256
    double s = 0.0;
#pragma unroll
    for (int k = t; k < KCODES; k += 256) {
        double p = (double)cnt[k] / (double)NPIX;
        s += p * log(p + 1e-10);
    }
#pragma unroll
    for (int o = 32; o > 0; o >>= 1) s += __shfl_xor(s, o, 64);
    __shared__ double rd[4];
    if ((t & 63) == 0) rd[t >> 6] = s;
    __syncthreads();
    if (t == 0) {
        double tot = rd[0] + rd[1] + rd[2] + rd[3];
        out[OUT_PERP_IDX] = (float)exp(-tot);
        out[0] = 0.25f * ws[0] / (float)NELEM;
    }
}

extern "C" void kernel_launch(void* const* d_in, const int* in_sizes, int n_in,
                              void* d_out, int out_size, void* d_ws, size_t ws_size,
                              hipStream_t stream) {
    const float* in  = (const float*)d_in[0];
    const float* emb = (const float*)d_in[1];
    float* out = (float*)d_out;
    float* ws  = (float*)d_ws;

    // zero loss accumulator + counts (ws is re-poisoned before every launch)
    hipMemsetAsync(d_ws, 0, (WS_CNT_OFF + KCODES) * sizeof(float), stream);
    vq_main<<<NPIX / 256, 256, 0, stream>>>(in, emb, out, ws);
    vq_fin<<<1, 256, 0, stream>>>(out, ws);
}

// Round 4
// 137.979 us; speedup vs baseline: 2.7434x; 2.2854x over previous
//
#include <hip/hip_runtime.h>
#include <math.h>

// Problem constants
#define NPIX   131072      // 32 * 64 * 64 pixels
#define KCODES 512
#define DDIM   64
#define HWSZ   4096        // 64*64
#define NELEM  8388608     // NPIX * DDIM

// d_out layout (fp32): [0]=loss, [1..1+NELEM)=q_nchw, [1+NELEM]=perplexity,
// [2+NELEM .. 2+2*NELEM)=q_nhwc flat
#define OUT_NCHW_OFF 1
#define OUT_PERP_IDX (1 + NELEM)
#define OUT_NHWC_OFF (2 + NELEM)

// ws layout (fp32 words): [0]=loss, [16..528)=|e|^2, [544..1056)=counts(uint),
// [2048..) = e bf16 hi/lo fragments in MFMA B-layout (byte 8192, 128KB)
#define WS_NRM_OFF  16
#define WS_CNT_OFF  544
#define WS_FRAG_F32 2048

typedef __bf16 bf16x8 __attribute__((ext_vector_type(8)));
typedef float  f32x4  __attribute__((ext_vector_type(4)));

__global__ __launch_bounds__(512) void vq_norms(const float* __restrict__ emb,
                                                float* __restrict__ ws) {
    int k = threadIdx.x;  // 512 threads; chain bit-identical to passing R1/R3 runs
    const float4* e4 = reinterpret_cast<const float4*>(emb + k * DDIM);
    float s = 0.f;
#pragma unroll
    for (int i = 0; i < 16; ++i) {
        float4 v = e4[i];
        s = fmaf(v.x, v.x, s); s = fmaf(v.y, v.y, s);
        s = fmaf(v.z, v.z, s); s = fmaf(v.w, v.w, s);
    }
    ws[WS_NRM_OFF + k] = s;
}

// Pack e into bf16 hi/lo MFMA B-fragments (16x16x32: B[k][n], n=lane&15,
// k=(lane>>4)*8+j). Thread tid = [ctile(32)][kstep(2)][h(2)][lane(64)] writes
// its lane's 8 bf16 = 16B, fully coalesced; vq_main loads frag at lane*16B.
__global__ __launch_bounds__(256) void vq_pack(const float* __restrict__ emb,
                                               float* __restrict__ ws) {
    int tid  = blockIdx.x * 256 + threadIdx.x;   // 0..8191
    int lane = tid & 63;
    int h    = (tid >> 6) & 1;
    int ks   = (tid >> 7) & 1;
    int ct   = tid >> 8;                         // 0..31
    int code = ct * 16 + (lane & 15);
    int d0   = ks * 32 + ((lane >> 4) & 3) * 8;
    const float* src = emb + code * DDIM + d0;
    unsigned short us[8];
#pragma unroll
    for (int j = 0; j < 8; ++j) {
        float f = src[j];
        __bf16 hb = (__bf16)f;                       // RTN
        if (h == 0) {
            us[j] = __builtin_bit_cast(unsigned short, hb);
        } else {
            __bf16 lb = (__bf16)(f - (float)hb);
            us[j] = __builtin_bit_cast(unsigned short, lb);
        }
    }
    uint4 v;
    v.x = us[0] | ((unsigned)us[1] << 16);
    v.y = us[2] | ((unsigned)us[3] << 16);
    v.z = us[4] | ((unsigned)us[5] << 16);
    v.w = us[6] | ((unsigned)us[7] << 16);
    reinterpret_cast<uint4*>(ws + WS_FRAG_F32)[tid] = v;
}

__global__ __launch_bounds__(256, 2) void vq_main(const float* __restrict__ in,
                                                  const float* __restrict__ emb,
                                                  float* __restrict__ out,
                                                  float* __restrict__ ws) {
    __shared__ __align__(16) float xs[256 * 68];  // x [pix][d] pad-68; reused as q tile
    __shared__ float    x2_lds[256];
    __shared__ float    nrm_lds[KCODES];
    __shared__ int      idx_lds[256];
    __shared__ unsigned cnt_lds[KCODES];
    __shared__ float    red_tot;

    const int t = threadIdx.x;
    cnt_lds[t] = 0u; cnt_lds[t + 256] = 0u;
    if (t == 0) red_tot = 0.f;

    const int pix0 = blockIdx.x << 8;
    const int b    = pix0 >> 12;
    const int hwb  = pix0 & (HWSZ - 1);

    // Stage x (thread t = pixel t): coalesced global reads, b128 LDS writes.
    const float* inb = in + b * (DDIM * HWSZ) + hwb + t;
    float x2 = 0.f;
#pragma unroll
    for (int c = 0; c < DDIM; c += 4) {
        float4 v;
        v.x = inb[(c + 0) * HWSZ]; v.y = inb[(c + 1) * HWSZ];
        v.z = inb[(c + 2) * HWSZ]; v.w = inb[(c + 3) * HWSZ];
        *reinterpret_cast<float4*>(&xs[t * 68 + c]) = v;
        x2 = fmaf(v.x, v.x, x2); x2 = fmaf(v.y, v.y, x2);
        x2 = fmaf(v.z, v.z, x2); x2 = fmaf(v.w, v.w, x2);
    }
    x2_lds[t] = x2;
    nrm_lds[t]       = ws[WS_NRM_OFF + t];
    nrm_lds[t + 256] = ws[WS_NRM_OFF + t + 256];
    __syncthreads();

    const int l = t & 63, wid = t >> 6;   // wave handles pixels [wid*64, +64)

    // A-fragments (A[m][k]: m=lane&15, k=(lane>>4)*8+j), hi/lo bf16 split.
    bf16x8 a_hi[4][2], a_lo[4][2];
#pragma unroll
    for (int pt = 0; pt < 4; ++pt)
#pragma unroll
    for (int ks = 0; ks < 2; ++ks) {
        int pixl = wid * 64 + pt * 16 + (l & 15);
        int d0   = ks * 32 + ((l >> 4) & 3) * 8;
        const float4* p = reinterpret_cast<const float4*>(&xs[pixl * 68 + d0]);
        float4 f0 = p[0], f1 = p[1];
        float fv[8] = {f0.x, f0.y, f0.z, f0.w, f1.x, f1.y, f1.z, f1.w};
        bf16x8 h8, l8;
#pragma unroll
        for (int j = 0; j < 8; ++j) {
            __bf16 hb = (__bf16)fv[j];
            h8[j] = hb;
            l8[j] = (__bf16)(fv[j] - (float)hb);
        }
        a_hi[pt][ks] = h8; a_lo[pt][ks] = l8;
    }

    const uint4* fragp = reinterpret_cast<const uint4*>(ws + WS_FRAG_F32);
    float best[4][4]; int bidx[4][4];
#pragma unroll
    for (int pt = 0; pt < 4; ++pt)
#pragma unroll
    for (int r = 0; r < 4; ++r) { best[pt][r] = 3.4e38f; bidx[pt][r] = 0; }

    // B-frag double buffer: 8 frags/chunk = [ct][ks][h]
    uint4 bcur[8], bnxt[8];
#pragma unroll
    for (int i = 0; i < 8; ++i) {
        int ct = i >> 2, ks = (i >> 1) & 1, h = i & 1;
        bcur[i] = fragp[(((ct) * 2 + ks) * 2 + h) * 64 + l];
    }

    for (int cb = 0; cb < KCODES; cb += 32) {
        int ctb = cb >> 4;
        if (cb + 32 < KCODES) {
#pragma unroll
            for (int i = 0; i < 8; ++i) {
                int ct = i >> 2, ks = (i >> 1) & 1, h = i & 1;
                bnxt[i] = fragp[(((ctb + 2 + ct) * 2 + ks) * 2 + h) * 64 + l];
            }
        }
        // 64 pix x 32 codes: 8 C-tiles, 4-term bf16 split accumulated in fp32
        f32x4 acc[4][2];
#pragma unroll
        for (int pt = 0; pt < 4; ++pt)
#pragma unroll
        for (int ct = 0; ct < 2; ++ct) {
            f32x4 a = {0.f, 0.f, 0.f, 0.f};
#pragma unroll
            for (int ks = 0; ks < 2; ++ks) {
                bf16x8 bh = __builtin_bit_cast(bf16x8, bcur[ct * 4 + ks * 2 + 0]);
                bf16x8 bl = __builtin_bit_cast(bf16x8, bcur[ct * 4 + ks * 2 + 1]);
                a = __builtin_amdgcn_mfma_f32_16x16x32_bf16(a_hi[pt][ks], bh, a, 0, 0, 0);
                a = __builtin_amdgcn_mfma_f32_16x16x32_bf16(a_hi[pt][ks], bl, a, 0, 0, 0);
                a = __builtin_amdgcn_mfma_f32_16x16x32_bf16(a_lo[pt][ks], bh, a, 0, 0, 0);
                a = __builtin_amdgcn_mfma_f32_16x16x32_bf16(a_lo[pt][ks], bl, a, 0, 0, 0);
            }
            acc[pt][ct] = a;
        }
        // argmin update; C/D: col(code)=lane&15, row(pix)=(lane>>4)*4+reg
#pragma unroll
        for (int ct = 0; ct < 2; ++ct) {
            int code = cb + ct * 16 + (l & 15);
            float nv = nrm_lds[code];
#pragma unroll
            for (int pt = 0; pt < 4; ++pt)
#pragma unroll
            for (int r = 0; r < 4; ++r) {
                float d = fmaf(-2.f, acc[pt][ct][r], nv);
                if (d < best[pt][r]) { best[pt][r] = d; bidx[pt][r] = code; }
            }
        }
#pragma unroll
        for (int i = 0; i < 8; ++i) bcur[i] = bnxt[i];
    }

    // Cross-lane argmin within each 16-lane group (codes spread over lane&15);
    // (dist, then idx) min = exact first-min semantics.
#pragma unroll
    for (int off = 1; off < 16; off <<= 1) {
#pragma unroll
        for (int pt = 0; pt < 4; ++pt)
#pragma unroll
        for (int r = 0; r < 4; ++r) {
            float ob = __shfl_xor(best[pt][r], off, 64);
            int   oi = __shfl_xor(bidx[pt][r], off, 64);
            bool take = (ob < best[pt][r]) || (ob == best[pt][r] && oi < bidx[pt][r]);
            if (take) { best[pt][r] = ob; bidx[pt][r] = oi; }
        }
    }
    if ((l & 15) == 0) {
        int q = l >> 4;
        float lp = 0.f;
#pragma unroll
        for (int pt = 0; pt < 4; ++pt)
#pragma unroll
        for (int r = 0; r < 4; ++r) {
            int pixl = wid * 64 + pt * 16 + q * 4 + r;
            idx_lds[pixl] = bidx[pt][r];
            atomicAdd(&cnt_lds[bidx[pt][r]], 1u);
            lp += x2_lds[pixl] + best[pt][r];   // |x-e|^2 = x^2 + (|e|^2 - 2x.e)
        }
        atomicAdd(&red_tot, lp);
    }
    __syncthreads();

    if (t == 0) atomicAdd(ws, red_tot);
    unsigned* gcnt = reinterpret_cast<unsigned*>(ws) + WS_CNT_OFF;
    atomicAdd(gcnt + t, cnt_lds[t]);
    atomicAdd(gcnt + t + 256, cnt_lds[t + 256]);

    // Epilogue (unchanged from R3, passing): padded LDS tile (aliases xs) makes
    // both NHWC and NCHW writes coalesced and LDS-conflict-free.
    float* q_lds = xs;                  // [64][65]
    float* out2 = out + OUT_NCHW_OFF;   // NCHW
    float* out3 = out + OUT_NHWC_OFF;   // NHWC flat (float2-aligned)
    const float2* emb2 = reinterpret_cast<const float2*>(emb);
    float2* out3_2 = reinterpret_cast<float2*>(out3);

    for (int s = 0; s < 4; ++s) {
#pragma unroll
        for (int it = 0; it < 8; ++it) {
            int fid = it * 256 + t;
            int pp  = fid >> 5;
            int c2  = fid & 31;
            int row = idx_lds[s * 64 + pp];
            float2 v = emb2[row * 32 + c2];
            out3_2[(size_t)(pix0 + s * 64 + pp) * 32 + c2] = v;
            q_lds[pp * 65 + c2 * 2 + 0] = v.x;
            q_lds[pp * 65 + c2 * 2 + 1] = v.y;
        }
        __syncthreads();
#pragma unroll
        for (int it = 0; it < 16; ++it) {
            int did = it * 256 + t;
            int c   = did >> 6;
            int hwl = did & 63;
            out2[(size_t)(b * DDIM + c) * HWSZ + hwb + s * 64 + hwl] = q_lds[hwl * 65 + c];
        }
        __syncthreads();
    }
}

__global__ __launch_bounds__(256) void vq_fin(float* __restrict__ out,
                                              const float* __restrict__ ws) {
    const unsigned* cnt = reinterpret_cast<const unsigned*>(ws) + WS_CNT_OFF;
    int t = threadIdx.x;  // 256
    double s = 0.0;
#pragma unroll
    for (int k = t; k < KCODES; k += 256) {
        double p = (double)cnt[k] / (double)NPIX;
        s += p * log(p + 1e-10);
    }
#pragma unroll
    for (int o = 32; o > 0; o >>= 1) s += __shfl_xor(s, o, 64);
    __shared__ double rd[4];
    if ((t & 63) == 0) rd[t >> 6] = s;
    __syncthreads();
    if (t == 0) {
        double tot = rd[0] + rd[1] + rd[2] + rd[3];
        out[OUT_PERP_IDX] = (float)exp(-tot);
        out[0] = 0.25f * ws[0] / (float)NELEM;
    }
}

extern "C" void kernel_launch(void* const* d_in, const int* in_sizes, int n_in,
                              void* d_out, int out_size, void* d_ws, size_t ws_size,
                              hipStream_t stream) {
    const float* in  = (const float*)d_in[0];
    const float* emb = (const float*)d_in[1];
    float* out = (float*)d_out;
    float* ws  = (float*)d_ws;

    // zero loss + norms + counts (frag region fully overwritten by vq_pack)
    hipMemsetAsync(d_ws, 0, (WS_CNT_OFF + KCODES) * sizeof(float), stream);
    vq_norms<<<1, 512, 0, stream>>>(emb, ws);
    vq_pack<<<32, 256, 0, stream>>>(emb, ws);
    vq_main<<<NPIX / 256, 256, 0, stream>>>(in, emb, out, ws);
    vq_fin<<<1, 256, 0, stream>>>(out, ws);
}